// Round 5
// baseline (4157.250 us; speedup 1.0000x reference)
//
#include <hip/hip_runtime.h>
#include <hip/hip_bf16.h>
#include <math.h>

#define B_ 32
#define NLOC 81
#define SBO 35
#define SPO 40
#define E_ 224
#define NH_ 8
#define DH 28
#define NLAYERS 10
#define LSTM_H 200
#define NACT 13030
#define NPOW 7
#define MAXL 17
#define TOK (B_*NLOC)          // 2592
#define NCOL (B_*NPOW)         // 224
#define NROW (NCOL*MAXL)       // 3808
#define DIST_SIZE (B_*NPOW*MAXL*NACT)  // 49618240 f32 elements

__device__ __forceinline__ float sigm(float x) { return 1.f / (1.f + __expf(-x)); }

// ---------------- encoder: x = concat(x_bo,x_po) @ enc_W^T + enc_b + pos_bias ----------------
__global__ __launch_bounds__(256) void encoder_kernel(
    const float* __restrict__ x_bo, const float* __restrict__ x_po,
    const float* __restrict__ enc_W, const float* __restrict__ enc_b,
    const float* __restrict__ pos_bias, float* __restrict__ x) {
  int t = blockIdx.x;           // token
  int l = t % NLOC;
  __shared__ float in[SBO + SPO];
  if (threadIdx.x < SBO) in[threadIdx.x] = x_bo[(size_t)t*SBO + threadIdx.x];
  else if (threadIdx.x < SBO + SPO) in[threadIdx.x] = x_po[(size_t)t*SPO + threadIdx.x - SBO];
  __syncthreads();
  int e = threadIdx.x;
  if (e < E_) {
    float s = enc_b[e] + pos_bias[l*E_ + e];
    const float* w = enc_W + e*(SBO+SPO);
    for (int k = 0; k < SBO+SPO; ++k) s += in[k] * w[k];
    x[(size_t)t*E_ + e] = s;
  }
}

// ---------------- generic GEMM: C[M,N] = A[M,K](f32) @ W[N,K]^T(f32) + bias ----------------
#define GBM 64
#define GBN 64
#define GBK 16
template<int RELU>
__global__ __launch_bounds__(256) void gemm_kernel(
    const float* __restrict__ A, const float* __restrict__ W,
    const float* __restrict__ bias, float* __restrict__ C,
    int M, int N, int K) {
  __shared__ float As[GBK][GBM+4];
  __shared__ float Ws[GBK][GBN+4];
  int tid = threadIdx.x;
  int tx = tid & 15, ty = tid >> 4;
  int row0 = blockIdx.y * GBM, col0 = blockIdx.x * GBN;
  float acc[4][4] = {};
  for (int k0 = 0; k0 < K; k0 += GBK) {
    for (int i = tid; i < GBM*GBK; i += 256) {
      int m = i >> 4, kk = i & 15;
      int gm = row0 + m, gk = k0 + kk;
      As[kk][m] = (gm < M && gk < K) ? A[(size_t)gm*K + gk] : 0.f;
    }
    for (int i = tid; i < GBN*GBK; i += 256) {
      int n = i >> 4, kk = i & 15;
      int gn = col0 + n, gk = k0 + kk;
      Ws[kk][n] = (gn < N && gk < K) ? W[(size_t)gn*K + gk] : 0.f;
    }
    __syncthreads();
#pragma unroll
    for (int kk = 0; kk < GBK; ++kk) {
      float4 av = *(const float4*)&As[kk][ty*4];
      float4 wv = *(const float4*)&Ws[kk][tx*4];
      float a_[4] = {av.x, av.y, av.z, av.w};
      float w_[4] = {wv.x, wv.y, wv.z, wv.w};
#pragma unroll
      for (int i = 0; i < 4; ++i)
#pragma unroll
        for (int j = 0; j < 4; ++j)
          acc[i][j] += a_[i] * w_[j];
    }
    __syncthreads();
  }
#pragma unroll
  for (int i = 0; i < 4; ++i) {
    int gm = row0 + ty*4 + i;
    if (gm >= M) continue;
#pragma unroll
    for (int j = 0; j < 4; ++j) {
      int gn = col0 + tx*4 + j;
      if (gn >= N) continue;
      float v = acc[i][j] + (bias ? bias[gn] : 0.f);
      if (RELU) v = fmaxf(v, 0.f);
      C[(size_t)gm*N + gn] = v;
    }
  }
}

// ---------------- attention (one block per (b,h)) ----------------
__global__ __launch_bounds__(256) void attn_kernel(const float* __restrict__ qkv,
                                                   float* __restrict__ attn_o) {
  int bh = blockIdx.x;
  int b = bh / NH_, h = bh % NH_;
  __shared__ float Qs[NLOC][DH];
  __shared__ float Ks[NLOC][DH+1];
  __shared__ float Vs[NLOC][DH+1];
  __shared__ float Ps[4][NLOC];
  for (int i = threadIdx.x; i < NLOC*DH; i += 256) {
    int l = i / DH, d = i % DH;
    const float* base = qkv + ((size_t)(b*NLOC + l))*(3*E_);
    Qs[l][d] = base[h*DH + d];
    Ks[l][d] = base[E_ + h*DH + d];
    Vs[l][d] = base[2*E_ + h*DH + d];
  }
  __syncthreads();
  int wave = threadIdx.x >> 6, lane = threadIdx.x & 63;
  const float scale = 0.1889822365046136f;  // 1/sqrt(28)
  for (int l = wave; l < NLOC; l += 4) {
    int j0 = lane, j1 = lane + 64;
    bool has1 = (j1 < NLOC);
    int j1c = has1 ? j1 : 0;
    float s0 = 0.f, s1 = 0.f;
    for (int d = 0; d < DH; ++d) {
      float q = Qs[l][d];
      s0 += q * Ks[j0][d];
      s1 += q * Ks[j1c][d];
    }
    s0 *= scale; s1 *= scale;
    float m = fmaxf(s0, has1 ? s1 : -1e30f);
    for (int off = 32; off; off >>= 1) m = fmaxf(m, __shfl_xor(m, off));
    float p0 = __expf(s0 - m);
    float p1 = has1 ? __expf(s1 - m) : 0.f;
    float sum = p0 + p1;
    for (int off = 32; off; off >>= 1) sum += __shfl_xor(sum, off);
    float inv = 1.f / sum;
    Ps[wave][j0] = p0 * inv;
    if (has1) Ps[wave][j1] = p1 * inv;
    if (lane < DH) {
      float o = 0.f;
      for (int j = 0; j < NLOC; ++j) o += Ps[wave][j] * Vs[j][lane];
      attn_o[((size_t)(b*NLOC + l))*E_ + h*DH + lane] = o;
    }
  }
}

// ---------------- x = LN(x + delta)*g + b (block per row) ----------------
__global__ __launch_bounds__(256) void addln_kernel(float* __restrict__ x,
                                                    const float* __restrict__ delta,
                                                    const float* __restrict__ g,
                                                    const float* __restrict__ bta) {
  int t = blockIdx.x;
  __shared__ float red[256];
  int e = threadIdx.x;
  float v = 0.f;
  if (e < E_) v = x[(size_t)t*E_ + e] + delta[(size_t)t*E_ + e];
  red[threadIdx.x] = (e < E_) ? v : 0.f;
  __syncthreads();
  for (int s = 128; s; s >>= 1) { if (threadIdx.x < s) red[threadIdx.x] += red[threadIdx.x+s]; __syncthreads(); }
  float mean = red[0] / E_;
  __syncthreads();
  float d = (e < E_) ? (v - mean) : 0.f;
  red[threadIdx.x] = d * d;
  __syncthreads();
  for (int s = 128; s; s >>= 1) { if (threadIdx.x < s) red[threadIdx.x] += red[threadIdx.x+s]; __syncthreads(); }
  float rstd = rsqrtf(red[0] / E_ + 1e-5f);
  if (e < E_) x[(size_t)t*E_ + e] = (v - mean) * rstd * g[e] + bta[e];
}

// ---------------- gather: seq[s][n][0:224]=x[b,locs_ix], [224:448]=msg_emb[b] ----------------
__global__ void gather_kernel(const float* __restrict__ x, const float* __restrict__ msg_emb,
                              const int* __restrict__ locs_ix, float* __restrict__ seq) {
  int idx = blockIdx.x*256 + threadIdx.x;
  if (idx >= MAXL*NCOL*(2*E_)) return;
  int k = idx % (2*E_);
  int rest = idx / (2*E_);
  int n = rest % NCOL, s = rest / NCOL;
  int b = n / NPOW;
  float v;
  if (k < E_) {
    int loc = locs_ix[n*MAXL + s];
    v = x[((size_t)(b*NLOC + loc))*E_ + k];
  } else {
    v = msg_emb[b*E_ + (k - E_)];
  }
  seq[idx] = v;
}

// ---------------- two-layer LSTM, 2 columns/block, 17 steps in-kernel ----------------
#define FMA8(q, va, vb, aa, ab) do { \
  (aa) += (q).x*(va).x + (q).y*(va).y + (q).z*(va).z + (q).w*(va).w; \
  (ab) += (q).x*(vb).x + (q).y*(vb).y + (q).z*(vb).z + (q).w*(vb).w; \
} while (0)

__global__ __launch_bounds__(256) void lstm_kernel(
    const float* __restrict__ gates0,   // [17*224, 800] = seq@Wih0^T + bih0
    const float* __restrict__ Whh0, const float* __restrict__ bhh0,
    const float* __restrict__ Wih1, const float* __restrict__ Whh1,
    const float* __restrict__ bih1, const float* __restrict__ bhh1,
    float* __restrict__ hs) {           // [224, 17, 200]
  int n0 = blockIdx.x * 2;
  int tid = threadIdx.x;
  __shared__ float hc[4][2][LSTM_H];    // h0,c0,h1,c1
  __shared__ float gar[2][800];
  for (int i = tid; i < 4*2*LSTM_H; i += 256) (&hc[0][0][0])[i] = 0.f;
  __syncthreads();
  int ga = tid, gb = tid + 256, gc = tid + 512;
  for (int s = 0; s < MAXL; ++s) {
    // ---- layer0: gar = gates0_row + bhh0 + h0 @ Whh0^T ----
    {
      const float* r0 = gates0 + ((size_t)s*NCOL + n0)*800;
      const float* r1 = r0 + 800;
      float a0 = r0[ga] + bhh0[ga], b0 = r1[ga] + bhh0[ga];
      float a1 = r0[gb] + bhh0[gb], b1 = r1[gb] + bhh0[gb];
      float a2 = r0[gc] + bhh0[gc], b2 = r1[gc] + bhh0[gc];
      const float* w0 = Whh0 + (size_t)ga*LSTM_H;
      const float* w1 = Whh0 + (size_t)gb*LSTM_H;
      const float* w2 = Whh0 + (size_t)gc*LSTM_H;
#pragma unroll 2
      for (int k = 0; k < LSTM_H; k += 4) {
        float4 va = *(const float4*)&hc[0][0][k];
        float4 vb = *(const float4*)&hc[0][1][k];
        float4 p0 = *(const float4*)(w0 + k);
        float4 p1 = *(const float4*)(w1 + k);
        float4 p2 = *(const float4*)(w2 + k);
        FMA8(p0, va, vb, a0, b0);
        FMA8(p1, va, vb, a1, b1);
        FMA8(p2, va, vb, a2, b2);
      }
      gar[0][ga] = a0; gar[1][ga] = b0;
      gar[0][gb] = a1; gar[1][gb] = b1;
      gar[0][gc] = a2; gar[1][gc] = b2;
      if (tid < 32) {
        int gd = tid + 768;
        float a3 = r0[gd] + bhh0[gd], b3 = r1[gd] + bhh0[gd];
        const float* w3 = Whh0 + (size_t)gd*LSTM_H;
#pragma unroll 2
        for (int k = 0; k < LSTM_H; k += 4) {
          float4 va = *(const float4*)&hc[0][0][k];
          float4 vb = *(const float4*)&hc[0][1][k];
          float4 p3 = *(const float4*)(w3 + k);
          FMA8(p3, va, vb, a3, b3);
        }
        gar[0][gd] = a3; gar[1][gd] = b3;
      }
    }
    __syncthreads();
    // ---- update layer0 ----
    for (int i = tid; i < 2*LSTM_H; i += 256) {
      int c = i / LSTM_H, j = i % LSTM_H;
      float ig = sigm(gar[c][j]);
      float fg = sigm(gar[c][200 + j]);
      float gg = tanhf(gar[c][400 + j]);
      float og = sigm(gar[c][600 + j]);
      float cc = fg * hc[1][c][j] + ig * gg;
      hc[1][c][j] = cc;
      hc[0][c][j] = og * tanhf(cc);
    }
    __syncthreads();
    // ---- layer1: gar = bih1+bhh1 + h0 @ Wih1^T + h1 @ Whh1^T ----
    {
      float a0 = bih1[ga] + bhh1[ga]; float b0 = a0;
      float a1 = bih1[gb] + bhh1[gb]; float b1 = a1;
      float a2 = bih1[gc] + bhh1[gc]; float b2 = a2;
      const float* u0 = Wih1 + (size_t)ga*LSTM_H;
      const float* u1 = Wih1 + (size_t)gb*LSTM_H;
      const float* u2 = Wih1 + (size_t)gc*LSTM_H;
#pragma unroll 2
      for (int k = 0; k < LSTM_H; k += 4) {
        float4 va = *(const float4*)&hc[0][0][k];
        float4 vb = *(const float4*)&hc[0][1][k];
        float4 p0 = *(const float4*)(u0 + k);
        float4 p1 = *(const float4*)(u1 + k);
        float4 p2 = *(const float4*)(u2 + k);
        FMA8(p0, va, vb, a0, b0);
        FMA8(p1, va, vb, a1, b1);
        FMA8(p2, va, vb, a2, b2);
      }
      const float* v0 = Whh1 + (size_t)ga*LSTM_H;
      const float* v1 = Whh1 + (size_t)gb*LSTM_H;
      const float* v2 = Whh1 + (size_t)gc*LSTM_H;
#pragma unroll 2
      for (int k = 0; k < LSTM_H; k += 4) {
        float4 va = *(const float4*)&hc[2][0][k];
        float4 vb = *(const float4*)&hc[2][1][k];
        float4 p0 = *(const float4*)(v0 + k);
        float4 p1 = *(const float4*)(v1 + k);
        float4 p2 = *(const float4*)(v2 + k);
        FMA8(p0, va, vb, a0, b0);
        FMA8(p1, va, vb, a1, b1);
        FMA8(p2, va, vb, a2, b2);
      }
      gar[0][ga] = a0; gar[1][ga] = b0;
      gar[0][gb] = a1; gar[1][gb] = b1;
      gar[0][gc] = a2; gar[1][gc] = b2;
      if (tid < 32) {
        int gd = tid + 768;
        float a3 = bih1[gd] + bhh1[gd]; float b3 = a3;
        const float* u3 = Wih1 + (size_t)gd*LSTM_H;
        const float* v3 = Whh1 + (size_t)gd*LSTM_H;
#pragma unroll 2
        for (int k = 0; k < LSTM_H; k += 4) {
          float4 va = *(const float4*)&hc[0][0][k];
          float4 vb = *(const float4*)&hc[0][1][k];
          float4 p3 = *(const float4*)(u3 + k);
          FMA8(p3, va, vb, a3, b3);
        }
#pragma unroll 2
        for (int k = 0; k < LSTM_H; k += 4) {
          float4 va = *(const float4*)&hc[2][0][k];
          float4 vb = *(const float4*)&hc[2][1][k];
          float4 p3 = *(const float4*)(v3 + k);
          FMA8(p3, va, vb, a3, b3);
        }
        gar[0][gd] = a3; gar[1][gd] = b3;
      }
    }
    __syncthreads();
    // ---- update layer1 + emit hs ----
    for (int i = tid; i < 2*LSTM_H; i += 256) {
      int c = i / LSTM_H, j = i % LSTM_H;
      float ig = sigm(gar[c][j]);
      float fg = sigm(gar[c][200 + j]);
      float gg = tanhf(gar[c][400 + j]);
      float og = sigm(gar[c][600 + j]);
      float cc = fg * hc[3][c][j] + ig * gg;
      hc[3][c][j] = cc;
      float hh = og * tanhf(cc);
      hc[2][c][j] = hh;
      hs[((size_t)(n0 + c)*MAXL + s)*LSTM_H + j] = hh;
    }
    __syncthreads();
  }
}

// ---------------- DENSE policy GEMM over ALL rows, mask fused into store, f32 out ----------------
__global__ __launch_bounds__(256) void pol_dense_kernel(
    const float* __restrict__ hs, const float* __restrict__ pol_W,
    const float* __restrict__ pol_b, const int* __restrict__ locs_len,
    float* __restrict__ out) {
  int row0 = blockIdx.y * 64, col0 = blockIdx.x * 64;
  __shared__ float As[GBK][68];
  __shared__ float Ws[GBK][68];
  int tid = threadIdx.x;
  int tx = tid & 15, ty = tid >> 4;
  float acc[4][4] = {};
  for (int k0 = 0; k0 < LSTM_H; k0 += GBK) {
    for (int i = tid; i < 64*GBK; i += 256) {
      int m = i >> 4, kk = i & 15;
      int gk = k0 + kk;
      int gm = row0 + m, gn = col0 + m;
      As[kk][m] = (gm < NROW && gk < LSTM_H) ? hs[(size_t)gm*LSTM_H + gk] : 0.f;
      Ws[kk][m] = (gn < NACT && gk < LSTM_H) ? pol_W[(size_t)gn*LSTM_H + gk] : 0.f;
    }
    __syncthreads();
#pragma unroll
    for (int kk = 0; kk < GBK; ++kk) {
      float4 av = *(const float4*)&As[kk][ty*4];
      float4 wv = *(const float4*)&Ws[kk][tx*4];
      float a_[4] = {av.x, av.y, av.z, av.w};
      float w_[4] = {wv.x, wv.y, wv.z, wv.w};
#pragma unroll
      for (int i = 0; i < 4; ++i)
#pragma unroll
        for (int j = 0; j < 4; ++j)
          acc[i][j] += a_[i] * w_[j];
    }
    __syncthreads();
  }
#pragma unroll
  for (int i = 0; i < 4; ++i) {
    int gm = row0 + ty*4 + i;
    if (gm >= NROW) continue;
    int n = gm / MAXL, s = gm % MAXL;
    bool live = (s < locs_len[n]);
#pragma unroll
    for (int j = 0; j < 4; ++j) {
      int gn = col0 + tx*4 + j;
      if (gn >= NACT) continue;
      float v = live ? (acc[i][j] + pol_b[gn]) : 0.f;
      out[(size_t)gm*NACT + gn] = v;
    }
  }
}

// ---------------- lin1 split-K partials: P[sk][32][224] ----------------
__global__ __launch_bounds__(256) void lin1_partial_kernel(
    const float* __restrict__ x, const float* __restrict__ msg_emb,
    const float* __restrict__ W, float* __restrict__ P) {
  const int K = NLOC*E_ + E_;   // 18368
  const int chunk = 1148;       // 16 * 1148 = 18368
  int sk = blockIdx.z;
  int kb = sk*chunk, ke = kb + chunk;
  int col0 = blockIdx.x*32;
  __shared__ float As[16][36];
  __shared__ float Ws[16][36];
  int tid = threadIdx.x;
  int tx = tid & 15, ty = tid >> 4;
  float a00=0.f, a01=0.f, a10=0.f, a11=0.f;
  for (int k0 = kb; k0 < ke; k0 += 16) {
    for (int i = tid; i < 32*16; i += 256) {
      int m = i >> 4, kk = i & 15;
      int gk = k0 + kk;
      float v = 0.f;
      if (gk < ke) v = (gk < NLOC*E_) ? x[(size_t)m*(NLOC*E_) + gk] : msg_emb[m*E_ + gk - NLOC*E_];
      As[kk][m] = v;
      int n = col0 + m;
      Ws[kk][m] = (gk < ke) ? W[(size_t)n*K + gk] : 0.f;
    }
    __syncthreads();
#pragma unroll
    for (int kk = 0; kk < 16; ++kk) {
      float a0 = As[kk][ty*2], a1 = As[kk][ty*2+1];
      float w0 = Ws[kk][tx*2], w1 = Ws[kk][tx*2+1];
      a00 += a0*w0; a01 += a0*w1; a10 += a1*w0; a11 += a1*w1;
    }
    __syncthreads();
  }
  float* Pd = P + (size_t)sk*32*224;
  Pd[(ty*2  )*224 + col0 + tx*2  ] = a00;
  Pd[(ty*2  )*224 + col0 + tx*2+1] = a01;
  Pd[(ty*2+1)*224 + col0 + tx*2  ] = a10;
  Pd[(ty*2+1)*224 + col0 + tx*2+1] = a11;
}

// ---------------- value finalize: relu(sum P + b) @ lin2^T + b2 -> out f32 ----------------
__global__ __launch_bounds__(256) void value_finalize_kernel(
    const float* __restrict__ P, const float* __restrict__ lin1_b,
    const float* __restrict__ lin2_W, const float* __restrict__ lin2_b,
    float* __restrict__ out) {
  __shared__ float v1[32*224];
  for (int idx = threadIdx.x; idx < 32*224; idx += 256) {
    float s = 0.f;
    for (int sk = 0; sk < 16; ++sk) s += P[(size_t)sk*32*224 + idx];
    s += lin1_b[idx % 224];
    v1[idx] = fmaxf(s, 0.f);
  }
  __syncthreads();
  if (threadIdx.x < 32*NPOW) {
    int m = threadIdx.x / NPOW, q = threadIdx.x % NPOW;
    float s = lin2_b[q];
    for (int n = 0; n < E_; ++n) s += v1[m*224 + n] * lin2_W[q*E_ + n];
    out[m*NPOW + q] = s;
  }
}

extern "C" void kernel_launch(void* const* d_in, const int* in_sizes, int n_in,
                              void* d_out, int out_size, void* d_ws, size_t ws_size,
                              hipStream_t stream) {
  (void)in_sizes; (void)n_in; (void)out_size; (void)ws_size;
  const float* x_bo    = (const float*)d_in[0];
  const float* x_po    = (const float*)d_in[1];
  const float* msg_log = (const float*)d_in[2];
  const float* enc_W   = (const float*)d_in[3];
  const float* enc_b   = (const float*)d_in[4];
  const float* pos_bias= (const float*)d_in[5];
  const float* Wqkv    = (const float*)d_in[6];
  const float* bqkv    = (const float*)d_in[7];
  const float* Wo      = (const float*)d_in[8];
  const float* bo      = (const float*)d_in[9];
  const float* ln1_g   = (const float*)d_in[10];
  const float* ln1_b   = (const float*)d_in[11];
  const float* W1      = (const float*)d_in[12];
  const float* b1      = (const float*)d_in[13];
  const float* W2      = (const float*)d_in[14];
  const float* b2      = (const float*)d_in[15];
  const float* ln2_g   = (const float*)d_in[16];
  const float* ln2_b   = (const float*)d_in[17];
  const float* msg_W   = (const float*)d_in[18];
  const float* msg_b   = (const float*)d_in[19];
  const float* Wih0    = (const float*)d_in[20];
  const float* Whh0    = (const float*)d_in[21];
  const float* bih0    = (const float*)d_in[22];
  const float* bhh0    = (const float*)d_in[23];
  const float* Wih1    = (const float*)d_in[24];
  const float* Whh1    = (const float*)d_in[25];
  const float* bih1    = (const float*)d_in[26];
  const float* bhh1    = (const float*)d_in[27];
  const float* pol_W   = (const float*)d_in[28];
  const float* pol_b   = (const float*)d_in[29];
  const float* lin1_W  = (const float*)d_in[30];
  const float* lin1_b  = (const float*)d_in[31];
  const float* lin2_W  = (const float*)d_in[32];
  const float* lin2_b  = (const float*)d_in[33];
  const int*   locs_ix = (const int*)d_in[34];
  const int*   locs_len= (const int*)d_in[35];

  // ---- persistent scratch in ws (~5.9 MB) ----
  float* ws = (float*)d_ws;
  float* x        = ws;                    // 580608
  float* msg_emb  = ws + 580608;           // 7168
  float* P        = ws + 587776;           // 114688 -> ends 702464
  float* hs       = ws + 702464;           // 761600 -> ends 1464064

  // ---- large transient scratch inside d_out's f32 dist region (49.6M f32 slots,
  //      fully rewritten by pol_dense at the end) ----
  float* os = (float*)d_out;
  float* qkv      = os;                    // 1741824
  float* attn_o   = os + 1741824;          // 580608
  float* tmp      = os + 2322432;          // 580608
  float* ff1      = os + 2903040;          // 580608 -> ends 3483648
  float* seq      = os;                    // 1705984 (reuses qkv area after transformer)
  float* gates0   = os + 3483648;          // 3046400 -> ends 6530048 (< 49618240)
  float* out      = (float*)d_out;

  // ---- encoder ----
  encoder_kernel<<<TOK, 256, 0, stream>>>(x_bo, x_po, enc_W, enc_b, pos_bias, x);

  // ---- transformer layers ----
  for (int l = 0; l < NLAYERS; ++l) {
    gemm_kernel<0><<<dim3(11, 41), 256, 0, stream>>>(
        x, Wqkv + (size_t)l*672*224, bqkv + l*672, qkv, TOK, 672, 224);
    attn_kernel<<<B_*NH_, 256, 0, stream>>>(qkv, attn_o);
    gemm_kernel<0><<<dim3(4, 41), 256, 0, stream>>>(
        attn_o, Wo + (size_t)l*224*224, bo + l*224, tmp, TOK, 224, 224);
    addln_kernel<<<TOK, 256, 0, stream>>>(x, tmp, ln1_g + l*224, ln1_b + l*224);
    gemm_kernel<1><<<dim3(4, 41), 256, 0, stream>>>(
        x, W1 + (size_t)l*224*224, b1 + l*224, ff1, TOK, 224, 224);
    gemm_kernel<0><<<dim3(4, 41), 256, 0, stream>>>(
        ff1, W2 + (size_t)l*224*224, b2 + l*224, tmp, TOK, 224, 224);
    addln_kernel<<<TOK, 256, 0, stream>>>(x, tmp, ln2_g + l*224, ln2_b + l*224);
  }

  // ---- message embedding: relu(msg_log @ msg_W^T + msg_b) ----
  gemm_kernel<1><<<dim3(4, 1), 256, 0, stream>>>(msg_log, msg_W, msg_b, msg_emb, 32, 224, 2000);

  // ---- LSTM input sequence + hoisted input-gate GEMM ----
  gather_kernel<<<(MAXL*NCOL*448 + 255)/256, 256, 0, stream>>>(x, msg_emb, locs_ix, seq);
  gemm_kernel<0><<<dim3(13, 60), 256, 0, stream>>>(seq, Wih0, bih0, gates0, NROW, 800, 448);
  lstm_kernel<<<NCOL/2, 256, 0, stream>>>(gates0, Whh0, bhh0, Wih1, Whh1, bih1, bhh1, hs);

  // ---- policy head: dense masked GEMM writes every dist element exactly once (f32) ----
  pol_dense_kernel<<<dim3((NACT + 63)/64, (NROW + 63)/64), 256, 0, stream>>>(
      hs, pol_W, pol_b, locs_len, out);

  // ---- value head ----
  lin1_partial_kernel<<<dim3(7, 1, 16), 256, 0, stream>>>(x, msg_emb, lin1_W, P);
  value_finalize_kernel<<<1, 256, 0, stream>>>(P, lin1_b, lin2_W, lin2_b, out + (size_t)DIST_SIZE);
}